// Round 6
// baseline (373.594 us; speedup 1.0000x reference)
//
#include <hip/hip_runtime.h>

// AttentionBlock: B=8, C=128, H=W=128, GROUPS=8, HEADS=8, HEAD_DIM=16
// R6 algebraic restructure: scores via raw Gram G = x x^T (+ row sums R):
//   S = As G As^T + v u^T + u v^T + N v v^T,  u = As R, As = w_in diag(s)
// GN stats from diag(G) and R. Pipeline:
//   k_gram  (256 blk): G[b] 128x128 + R[b] via bf16 MFMA, dbuf LDS, atomics
//   k_prep2 (8 blk):   stats -> s,t,v,u ; As(bf16) ; P=As G ; S=P As^T ;
//                      softmax ; w_eff(bf16)
//   k_out   (2048 blk): GEMM1 + GEMM2 + residual (x from staged LDS, no re-read)

#define NPOS 16384

typedef short short8 __attribute__((ext_vector_type(8)));   // 8 bf16
typedef float f32x4 __attribute__((ext_vector_type(4)));

__device__ __forceinline__ unsigned short f2bf(float f) {
    union { float f; unsigned u; } v; v.f = f;
    unsigned r = (v.u + 0x7fffu + ((v.u >> 16) & 1u)) >> 16;
    return (unsigned short)r;
}
__device__ __forceinline__ float bf2f(unsigned short h) {
    union { unsigned u; float f; } v; v.u = ((unsigned)h) << 16;
    return v.f;
}

// ---------------- K1: per-batch Gram G = X X^T and row sums R ----------------
// 256 blocks: b = blk>>5, p-slab = (blk&31)*512. 8 chunks of 64 pos, dbuf.
// Wave w owns row-blocks {2w, 2w+1} x all 8 col-blocks + ones-column.
__global__ __launch_bounds__(256) void k_gram(const float* __restrict__ x,
                                              float* __restrict__ Gws) {
    __shared__ unsigned short Xs[2][8192];   // [k][64p], chunk-swizzled

    const int t = threadIdx.x;
    const int lane = t & 63, wv = t >> 6;
    const int q = lane >> 4, i16 = lane & 15;
    const int b = blockIdx.x >> 5;
    const int slab0 = (blockIdx.x & 31) << 9;
    const float* xb = x + (size_t)b * (128 * NPOS) + slab0;

    const int pc = t & 7;        // p-chunk within 64 (8 pos each)
    const int kr0 = t >> 3;      // 0..31 base channel row

    short8 ones;
#pragma unroll
    for (int e = 0; e < 8; ++e) ((unsigned short*)&ones)[e] = 0x3F80;

    f32x4 acc[2][8];
    f32x4 ao[2];
#pragma unroll
    for (int i2 = 0; i2 < 2; ++i2) {
        ao[i2] = (f32x4){0.f, 0.f, 0.f, 0.f};
#pragma unroll
        for (int j = 0; j < 8; ++j) acc[i2][j] = (f32x4){0.f, 0.f, 0.f, 0.f};
    }

    // stage chunk 0
#pragma unroll
    for (int i = 0; i < 4; ++i) {
        int k = kr0 + i * 32;
        const float4* src = (const float4*)(xb + (size_t)k * NPOS + pc * 8);
        float4 v0 = src[0], v1 = src[1];
        short8 o;
        ((unsigned short*)&o)[0] = f2bf(v0.x); ((unsigned short*)&o)[1] = f2bf(v0.y);
        ((unsigned short*)&o)[2] = f2bf(v0.z); ((unsigned short*)&o)[3] = f2bf(v0.w);
        ((unsigned short*)&o)[4] = f2bf(v1.x); ((unsigned short*)&o)[5] = f2bf(v1.y);
        ((unsigned short*)&o)[6] = f2bf(v1.z); ((unsigned short*)&o)[7] = f2bf(v1.w);
        *(short8*)&Xs[0][k * 64 + ((pc ^ (k & 7)) << 3)] = o;
    }
    __syncthreads();

    for (int cc = 0; cc < 8; ++cc) {
        if (cc < 7) {
            int bf = (cc + 1) & 1;
            int pbase = (cc + 1) * 64 + pc * 8;
#pragma unroll
            for (int i = 0; i < 4; ++i) {
                int k = kr0 + i * 32;
                const float4* src = (const float4*)(xb + (size_t)k * NPOS + pbase);
                float4 v0 = src[0], v1 = src[1];
                short8 o;
                ((unsigned short*)&o)[0] = f2bf(v0.x); ((unsigned short*)&o)[1] = f2bf(v0.y);
                ((unsigned short*)&o)[2] = f2bf(v0.z); ((unsigned short*)&o)[3] = f2bf(v0.w);
                ((unsigned short*)&o)[4] = f2bf(v1.x); ((unsigned short*)&o)[5] = f2bf(v1.y);
                ((unsigned short*)&o)[6] = f2bf(v1.z); ((unsigned short*)&o)[7] = f2bf(v1.w);
                *(short8*)&Xs[bf][k * 64 + ((pc ^ (k & 7)) << 3)] = o;
            }
        }
        const unsigned short* Xb = Xs[cc & 1];
#pragma unroll
        for (int kk = 0; kk < 2; ++kk) {
            short8 f[8];
#pragma unroll
            for (int r = 0; r < 8; ++r) {
                int row = r * 16 + i16;
                f[r] = *(const short8*)&Xb[row * 64 + (((kk * 4 + q) ^ (row & 7)) << 3)];
            }
#pragma unroll
            for (int i2 = 0; i2 < 2; ++i2) {
                short8 fa = f[wv * 2 + i2];
                ao[i2] = __builtin_amdgcn_mfma_f32_16x16x32_bf16(fa, ones, ao[i2], 0, 0, 0);
#pragma unroll
                for (int j = 0; j < 8; ++j)
                    acc[i2][j] = __builtin_amdgcn_mfma_f32_16x16x32_bf16(fa, f[j], acc[i2][j], 0, 0, 0);
            }
        }
        __syncthreads();
    }

    float* Gb = Gws + b * 16512;
#pragma unroll
    for (int i2 = 0; i2 < 2; ++i2) {
        int rbase = (wv * 2 + i2) * 16 + q * 4;
#pragma unroll
        for (int j = 0; j < 8; ++j)
#pragma unroll
            for (int r = 0; r < 4; ++r)
                atomicAdd(&Gb[(rbase + r) * 128 + j * 16 + i16], acc[i2][j][r]);
        if (i16 == 0)
#pragma unroll
            for (int r = 0; r < 4; ++r)
                atomicAdd(&Gb[16384 + rbase + r], ao[i2][r]);
    }
}

// ---------------- K2: everything small (per batch) ----------------
__global__ __launch_bounds__(256) void k_prep2(const float* __restrict__ Gws,
                                               const float* __restrict__ gn_w,
                                               const float* __restrict__ gn_b,
                                               const float* __restrict__ w_in,
                                               const float* __restrict__ b_in,
                                               const float* __restrict__ w_out,
                                               float* __restrict__ vA,
                                               unsigned short* __restrict__ Asb,
                                               unsigned short* __restrict__ weffb) {
    __shared__ float s_l[128], t_l[128], v_l[128], u_l[128];
    __shared__ float tmpA[128], tmpB[128], red[16];
    __shared__ unsigned short As_l[16384];   // [c][k] swz
    __shared__ unsigned short Gb_l[16384];   // [l][k] swz (G symmetric)
    __shared__ unsigned short Pb_l[16384];   // [c][l] swz
    __shared__ float Wl[2048];

    const int t = threadIdx.x;
    const int lane = t & 63, wv = t >> 6;
    const int q = lane >> 4, i16 = lane & 15;
    const int b = blockIdx.x;
    const float* Gb = Gws + b * 16512;
    const float* Rb = Gb + 16384;

    // Phase A: stats -> s,t,v,u
    if (t < 128) { tmpA[t] = Gb[t * 128 + t]; tmpB[t] = Rb[t]; }
    __syncthreads();
    if (t < 8) {
        float s2 = 0.f, s1 = 0.f;
#pragma unroll
        for (int k = 0; k < 16; ++k) { s2 += tmpA[t * 16 + k]; s1 += tmpB[t * 16 + k]; }
        const float invN = 1.0f / 262144.0f;
        float mean = s1 * invN;
        float var = s2 * invN - mean * mean;
        red[t] = mean;
        red[8 + t] = rsqrtf(var + 1e-5f);
    }
    __syncthreads();
    if (t < 128) {
        int g = t >> 4;
        float s = gn_w[t] * red[8 + g];
        s_l[t] = s;
        t_l[t] = gn_b[t] - red[g] * s;
    }
    __syncthreads();
    if (t < 128) {
        float v = b_in[t], u = 0.f;
        const float* wr = w_in + t * 128;
#pragma unroll 8
        for (int k = 0; k < 128; ++k) {
            float w = wr[k];
            v += w * t_l[k];
            u += w * s_l[k] * tmpB[k];
        }
        v_l[t] = v; u_l[t] = u;
        vA[b * 128 + t] = v;
    }
    __syncthreads();

    // Phase B: stage As (bf16, swz + global) and G (bf16, swz)
    {
        const float4* w4 = (const float4*)w_in;
        const float4* g4 = (const float4*)Gb;
        unsigned short* abg = Asb + b * 16384;
#pragma unroll
        for (int rep = 0; rep < 16; ++rep) {
            int idx4 = t + rep * 256;
            int c = idx4 >> 5, k0 = (idx4 & 31) * 4;
            int addr = c * 128 + ((((k0 >> 3) ^ (c & 7)) << 3)) + (k0 & 7);
            float4 w = w4[idx4];
            ushort4 o;
            o.x = f2bf(w.x * s_l[k0 + 0]); o.y = f2bf(w.y * s_l[k0 + 1]);
            o.z = f2bf(w.z * s_l[k0 + 2]); o.w = f2bf(w.w * s_l[k0 + 3]);
            *(ushort4*)&As_l[addr] = o;
            *(ushort4*)&abg[c * 128 + k0] = o;
            float4 g = g4[idx4];
            ushort4 og;
            og.x = f2bf(g.x); og.y = f2bf(g.y); og.z = f2bf(g.z); og.w = f2bf(g.w);
            *(ushort4*)&Gb_l[addr] = og;
        }
    }
    __syncthreads();

    // Phase C: P = As @ G  (D[m=c][n=l])
    {
        f32x4 pacc[2][8];
#pragma unroll
        for (int i2 = 0; i2 < 2; ++i2)
#pragma unroll
            for (int j = 0; j < 8; ++j) pacc[i2][j] = (f32x4){0.f, 0.f, 0.f, 0.f};
#pragma unroll
        for (int kk = 0; kk < 4; ++kk) {
            int ch = ((kk * 4 + q) ^ (i16 & 7)) << 3;
            short8 fa[2], fb[8];
#pragma unroll
            for (int i2 = 0; i2 < 2; ++i2)
                fa[i2] = *(const short8*)&As_l[((wv * 2 + i2) * 16 + i16) * 128 + ch];
#pragma unroll
            for (int j = 0; j < 8; ++j)
                fb[j] = *(const short8*)&Gb_l[(j * 16 + i16) * 128 + ch];
#pragma unroll
            for (int i2 = 0; i2 < 2; ++i2)
#pragma unroll
                for (int j = 0; j < 8; ++j)
                    pacc[i2][j] = __builtin_amdgcn_mfma_f32_16x16x32_bf16(fa[i2], fb[j], pacc[i2][j], 0, 0, 0);
        }
        // P -> bf16 LDS [c][l] swz
#pragma unroll
        for (int i2 = 0; i2 < 2; ++i2) {
#pragma unroll
            for (int j = 0; j < 8; ++j) {
#pragma unroll
                for (int r = 0; r < 4; ++r) {
                    int c = (wv * 2 + i2) * 16 + q * 4 + r;
                    int l = j * 16 + i16;
                    Pb_l[c * 128 + ((((l >> 3) ^ (c & 7)) << 3)) + (l & 7)] = f2bf(pacc[i2][j][r]);
                }
            }
        }
    }
    __syncthreads();

    // Phase D: per head S = P_h As_h^T ; logits ; softmax -> Wl
#pragma unroll
    for (int hh = 0; hh < 2; ++hh) {
        int h = wv * 2 + hh;
        f32x4 sacc = (f32x4){0.f, 0.f, 0.f, 0.f};
#pragma unroll
        for (int kk = 0; kk < 4; ++kk) {
            int ch = ((kk * 4 + q) ^ (i16 & 7)) << 3;
            short8 fa = *(const short8*)&Pb_l[(h * 16 + i16) * 128 + ch];
            short8 fb = *(const short8*)&As_l[(h * 16 + i16) * 128 + ch];
            sacc = __builtin_amdgcn_mfma_f32_16x16x32_bf16(fa, fb, sacc, 0, 0, 0);
        }
        int cn = h * 16 + i16;
#pragma unroll
        for (int r = 0; r < 4; ++r) {
            int cm = h * 16 + q * 4 + r;
            float L = 0.25f * (sacc[r] + v_l[cm] * u_l[cn] + u_l[cm] * v_l[cn]
                               + 16384.f * v_l[cm] * v_l[cn]);
            float m = L;
#pragma unroll
            for (int d = 1; d < 16; d <<= 1) m = fmaxf(m, __shfl_xor(m, d, 16));
            float e = __expf(L - m);
            float sum = e;
#pragma unroll
            for (int d = 1; d < 16; d <<= 1) sum += __shfl_xor(sum, d, 16);
            Wl[(h * 16 + q * 4 + r) * 16 + i16] = e / sum;
        }
    }
    __syncthreads();

    // Phase E: w_eff = w_out @ blockdiag(W) -> bf16
    {
        unsigned short* wo = weffb + b * 16384;
#pragma unroll 2
        for (int rep = 0; rep < 64; ++rep) {
            int idx = t + rep * 256;
            int c = idx >> 7, col = idx & 127;
            int h = col >> 4, n = col & 15;
            const float* wr = w_out + c * 128 + h * 16;
            const float* Wr = Wl + h * 256 + n;
            float a = 0.f;
#pragma unroll
            for (int m = 0; m < 16; ++m) a += wr[m] * Wr[m * 16];
            wo[idx] = f2bf(a);
        }
    }
}

// ---------------- K3: GEMM1 + GEMM2 + residual (x kept in LDS) ----------------
__global__ __launch_bounds__(256, 4) void k_out(const float* __restrict__ x,
                                                const unsigned short* __restrict__ Asb,
                                                const float* __restrict__ vA,
                                                const unsigned short* __restrict__ weffb,
                                                const float* __restrict__ b_out,
                                                float* __restrict__ out) {
    __shared__ unsigned short Xs[8192];   // x-stage [p][k] swz, persistent
    __shared__ unsigned short Ht[8192];   // h1^T [p][c] swz, then Hb [c][p] swz
    __shared__ float v_s[128];
    __shared__ float bo_s[128];

    const int t = threadIdx.x;
    const int lane = t & 63, wv = t >> 6;
    const int q = lane >> 4, i16 = lane & 15;
    const int b = blockIdx.x >> 8;
    const int p0 = (blockIdx.x & 255) << 6;
    const float* xb = x + (size_t)b * (128 * NPOS) + p0;

    if (t < 128) { v_s[t] = vA[b * 128 + t]; bo_s[t] = b_out[t]; }

    // stage Xs[p][k] = bf16(x[k][p0+p]); chunk (k>>3) ^ (p&15)
    {
        const int p = t & 63;
        const int sw = p & 15;
        const int kq0 = t >> 6;
#pragma unroll
        for (int i = 0; i < 4; ++i) {
            int kq = kq0 + i * 4;
            const float* col = xb + (size_t)(kq * 8) * NPOS + p;
            short8 o;
#pragma unroll
            for (int e = 0; e < 8; ++e)
                ((unsigned short*)&o)[e] = f2bf(col[(size_t)e * NPOS]);
            *(short8*)&Xs[p * 128 + ((kq ^ sw) << 3)] = o;
        }
    }
    __syncthreads();

    // GEMM1: A = Asb (global), B = Xs
    const unsigned short* ab = Asb + b * 16384;
    f32x4 acc1[2][4];
#pragma unroll
    for (int a = 0; a < 2; ++a)
#pragma unroll
        for (int pt = 0; pt < 4; ++pt) acc1[a][pt] = (f32x4){0.f, 0.f, 0.f, 0.f};

#pragma unroll
    for (int ks = 0; ks < 4; ++ks) {
        short8 a0 = *(const short8*)&ab[(wv * 32 + i16) * 128 + ks * 32 + q * 8];
        short8 a1 = *(const short8*)&ab[(wv * 32 + 16 + i16) * 128 + ks * 32 + q * 8];
        const int cb = ((ks * 4 + q) ^ i16) << 3;
#pragma unroll
        for (int pt = 0; pt < 4; ++pt) {
            short8 bb = *(const short8*)&Xs[(pt * 16 + i16) * 128 + cb];
            acc1[0][pt] = __builtin_amdgcn_mfma_f32_16x16x32_bf16(a0, bb, acc1[0][pt], 0, 0, 0);
            acc1[1][pt] = __builtin_amdgcn_mfma_f32_16x16x32_bf16(a1, bb, acc1[1][pt], 0, 0, 0);
        }
    }

    // h1^T -> Ht[p][c] (+v), chunk swizzle (c>>3) ^ (p&15)
#pragma unroll
    for (int a = 0; a < 2; ++a) {
        int cb0 = wv * 32 + a * 16 + q * 4;
#pragma unroll
        for (int pt = 0; pt < 4; ++pt) {
            int p = pt * 16 + i16;
#pragma unroll
            for (int r = 0; r < 4; ++r) {
                int c = cb0 + r;
                Ht[p * 128 + ((((c >> 3) ^ i16) << 3)) + (c & 7)] =
                    f2bf(acc1[a][pt][r] + v_s[c]);
            }
        }
    }
    __syncthreads();

    // GEMM2: A = weff (global), B = h1^T (LDS)
    const unsigned short* ab2 = weffb + b * 16384;
    f32x4 acc2[2][4];
#pragma unroll
    for (int a = 0; a < 2; ++a)
#pragma unroll
        for (int pt = 0; pt < 4; ++pt) acc2[a][pt] = (f32x4){0.f, 0.f, 0.f, 0.f};

#pragma unroll
    for (int ks = 0; ks < 4; ++ks) {
        short8 a0 = *(const short8*)&ab2[(wv * 32 + i16) * 128 + ks * 32 + q * 8];
        short8 a1 = *(const short8*)&ab2[(wv * 32 + 16 + i16) * 128 + ks * 32 + q * 8];
        const int cb = ((ks * 4 + q) ^ i16) << 3;
#pragma unroll
        for (int pt = 0; pt < 4; ++pt) {
            short8 bb = *(const short8*)&Ht[(pt * 16 + i16) * 128 + cb];
            acc2[0][pt] = __builtin_amdgcn_mfma_f32_16x16x32_bf16(a0, bb, acc2[0][pt], 0, 0, 0);
            acc2[1][pt] = __builtin_amdgcn_mfma_f32_16x16x32_bf16(a1, bb, acc2[1][pt], 0, 0, 0);
        }
    }
    __syncthreads();

    // Hb[c][p] = acc2 + b_out, p-chunk swizzle (p>>3) ^ (c&7)
#pragma unroll
    for (int a = 0; a < 2; ++a) {
        int cb0 = wv * 32 + a * 16 + q * 4;
#pragma unroll
        for (int pt = 0; pt < 4; ++pt) {
            int p = pt * 16 + i16;
#pragma unroll
            for (int r = 0; r < 4; ++r) {
                int c = cb0 + r;
                Ht[c * 64 + ((((p >> 3) ^ (c & 7)) << 3)) + (p & 7)] =
                    f2bf(acc2[a][pt][r] + bo_s[c]);
            }
        }
    }
    __syncthreads();

    // epilogue: out = x(LDS bf16) + h ; float4 stores
    float* ob = out + (size_t)b * (128 * NPOS) + p0;
#pragma unroll
    for (int i = 0; i < 8; ++i) {
        int idx = t + i * 256;
        int c = idx >> 4, p4 = idx & 15;
        int p = p4 * 4;
        ushort4 hv = *(const ushort4*)&Ht[c * 64 + ((((p >> 3) ^ (c & 7)) << 3)) + (p & 7)];
        float4 o;
        o.x = bf2f(Xs[(p + 0) * 128 + ((((c >> 3) ^ ((p + 0) & 15)) << 3)) + (c & 7)]) + bf2f(hv.x);
        o.y = bf2f(Xs[(p + 1) * 128 + ((((c >> 3) ^ ((p + 1) & 15)) << 3)) + (c & 7)]) + bf2f(hv.y);
        o.z = bf2f(Xs[(p + 2) * 128 + ((((c >> 3) ^ ((p + 2) & 15)) << 3)) + (c & 7)]) + bf2f(hv.z);
        o.w = bf2f(Xs[(p + 3) * 128 + ((((c >> 3) ^ ((p + 3) & 15)) << 3)) + (c & 7)]) + bf2f(hv.w);
        *(float4*)&ob[(size_t)c * NPOS + p] = o;
    }
}

extern "C" void kernel_launch(void* const* d_in, const int* in_sizes, int n_in,
                              void* d_out, int out_size, void* d_ws, size_t ws_size,
                              hipStream_t stream) {
    const float* x    = (const float*)d_in[0];
    const float* gn_w = (const float*)d_in[1];
    const float* gn_b = (const float*)d_in[2];
    const float* w_in = (const float*)d_in[3];
    const float* b_in = (const float*)d_in[4];
    const float* w_out= (const float*)d_in[5];
    const float* b_out= (const float*)d_in[6];
    float* out = (float*)d_out;

    float* ws = (float*)d_ws;
    float* Gws = ws;                                          // 8 x (16384 G + 128 R)
    float* vA  = ws + 132096;                                 // 1024 f
    unsigned short* Asb   = (unsigned short*)(ws + 133120);   // 131072 us
    unsigned short* weffb = (unsigned short*)(ws + 198656);   // 131072 us

    hipMemsetAsync(d_ws, 0, 132096 * sizeof(float), stream);
    k_gram<<<dim3(256), dim3(256), 0, stream>>>(x, Gws);
    k_prep2<<<dim3(8), dim3(256), 0, stream>>>(Gws, gn_w, gn_b, w_in, b_in, w_out,
                                               vA, Asb, weffb);
    k_out<<<dim3(2048), dim3(256), 0, stream>>>(x, Asb, vA, weffb, b_out, out);
}

// Round 7
// 209.898 us; speedup vs baseline: 1.7799x; 1.7799x over previous
//
#include <hip/hip_runtime.h>

// AttentionBlock: B=8, C=128, H=W=128, GROUPS=8, HEADS=8, HEAD_DIM=16
// R7: Gram pipeline (R6 algebra, proven correct) with k_gram rebuilt for
// occupancy: 512 blocks x 1024 threads (16 waves: row-tile x col-half split,
// 4 acc tiles/wave), float4 coalesced staging (x is [c][p] -> no transpose
// needed for Gram), dbuf LDS. k_prep2 / k_out unchanged from R6.
//   S = As G As^T + v u^T + u v^T + N v v^T,  u = As R, As = w_in diag(s)
//   k_gram (512 blk x 1024): G[b] + R[b] via bf16 MFMA, atomics
//   k_prep2 (8 blk): stats -> s,t,v,u ; As ; P=As G ; S ; softmax ; w_eff
//   k_out  (2048 blk): GEMM1 + GEMM2 + residual (x from staged LDS)

#define NPOS 16384

typedef short short8 __attribute__((ext_vector_type(8)));   // 8 bf16
typedef float f32x4 __attribute__((ext_vector_type(4)));

__device__ __forceinline__ unsigned short f2bf(float f) {
    union { float f; unsigned u; } v; v.f = f;
    unsigned r = (v.u + 0x7fffu + ((v.u >> 16) & 1u)) >> 16;
    return (unsigned short)r;
}
__device__ __forceinline__ float bf2f(unsigned short h) {
    union { unsigned u; float f; } v; v.u = ((unsigned)h) << 16;
    return v.f;
}

// ---------------- K1: per-batch Gram G = X X^T and row sums R ----------------
// 512 blocks x 1024 thr: b = blk>>6, 256-pos slab. 4 chunks of 64 pos, dbuf.
// Wave w: row-tile rt=w&7, col-half ch=w>>3 (4 col-tiles) -> 4 acc tiles.
__global__ __launch_bounds__(1024) void k_gram(const float* __restrict__ x,
                                               float* __restrict__ Gws) {
    __shared__ unsigned short Xs[2][8192];   // [c][64p] bf16, chunk-swizzled

    const int t = threadIdx.x;
    const int lane = t & 63, wv = t >> 6;    // 16 waves
    const int q = lane >> 4, i16 = lane & 15;
    const int b = blockIdx.x >> 6;
    const int slab0 = (blockIdx.x & 63) << 8;
    const float* xb = x + (size_t)b * (128 * NPOS) + slab0;

    const int rt = wv & 7;                   // row-tile 0..7
    const int ch = wv >> 3;                  // col half 0..1

    short8 ones;
#pragma unroll
    for (int e = 0; e < 8; ++e) ((unsigned short*)&ones)[e] = 0x3F80;

    f32x4 acc[4];
    f32x4 ra = (f32x4){0.f, 0.f, 0.f, 0.f};
#pragma unroll
    for (int j = 0; j < 4; ++j) acc[j] = (f32x4){0.f, 0.f, 0.f, 0.f};

    // stage chunk 0
#pragma unroll
    for (int i = 0; i < 2; ++i) {
        int idx4 = t + i * 1024;
        int c = idx4 >> 4, p4 = idx4 & 15;
        float4 v = *(const float4*)(xb + (size_t)c * NPOS + p4 * 4);
        ushort4 o;
        o.x = f2bf(v.x); o.y = f2bf(v.y); o.z = f2bf(v.z); o.w = f2bf(v.w);
        *(ushort4*)&Xs[0][c * 64 + ((((p4 >> 1) ^ (c & 7)) << 3)) + (p4 & 1) * 4] = o;
    }
    __syncthreads();

    for (int cc = 0; cc < 4; ++cc) {
        if (cc < 3) {
            int bf = (cc + 1) & 1;
            int pb = (cc + 1) * 64;
#pragma unroll
            for (int i = 0; i < 2; ++i) {
                int idx4 = t + i * 1024;
                int c = idx4 >> 4, p4 = idx4 & 15;
                float4 v = *(const float4*)(xb + (size_t)c * NPOS + pb + p4 * 4);
                ushort4 o;
                o.x = f2bf(v.x); o.y = f2bf(v.y); o.z = f2bf(v.z); o.w = f2bf(v.w);
                *(ushort4*)&Xs[bf][c * 64 + ((((p4 >> 1) ^ (c & 7)) << 3)) + (p4 & 1) * 4] = o;
            }
        }
        const unsigned short* Xb = Xs[cc & 1];
#pragma unroll
        for (int kk = 0; kk < 2; ++kk) {
            int kq = kk * 4 + q;
            int ar = rt * 16 + i16;
            short8 fa = *(const short8*)&Xb[ar * 64 + ((kq ^ (ar & 7)) << 3)];
            if (ch == 0)
                ra = __builtin_amdgcn_mfma_f32_16x16x32_bf16(fa, ones, ra, 0, 0, 0);
#pragma unroll
            for (int j = 0; j < 4; ++j) {
                int cb = (ch * 4 + j) * 16 + i16;
                short8 fb = *(const short8*)&Xb[cb * 64 + ((kq ^ (cb & 7)) << 3)];
                acc[j] = __builtin_amdgcn_mfma_f32_16x16x32_bf16(fa, fb, acc[j], 0, 0, 0);
            }
        }
        __syncthreads();
    }

    float* Gb = Gws + b * 16512;
    const int rbase = rt * 16 + q * 4;
#pragma unroll
    for (int j = 0; j < 4; ++j) {
        int col = (ch * 4 + j) * 16 + i16;
#pragma unroll
        for (int r = 0; r < 4; ++r)
            atomicAdd(&Gb[(rbase + r) * 128 + col], acc[j][r]);
    }
    if (ch == 0 && i16 == 0)
#pragma unroll
        for (int r = 0; r < 4; ++r)
            atomicAdd(&Gb[16384 + rbase + r], ra[r]);
}

// ---------------- K2: everything small (per batch) ----------------
__global__ __launch_bounds__(256) void k_prep2(const float* __restrict__ Gws,
                                               const float* __restrict__ gn_w,
                                               const float* __restrict__ gn_b,
                                               const float* __restrict__ w_in,
                                               const float* __restrict__ b_in,
                                               const float* __restrict__ w_out,
                                               float* __restrict__ vA,
                                               unsigned short* __restrict__ Asb,
                                               unsigned short* __restrict__ weffb) {
    __shared__ float s_l[128], t_l[128], v_l[128], u_l[128];
    __shared__ float tmpA[128], tmpB[128], red[16];
    __shared__ unsigned short As_l[16384];   // [c][k] swz
    __shared__ unsigned short Gb_l[16384];   // [l][k] swz (G symmetric)
    __shared__ unsigned short Pb_l[16384];   // [c][l] swz
    __shared__ float Wl[2048];

    const int t = threadIdx.x;
    const int lane = t & 63, wv = t >> 6;
    const int q = lane >> 4, i16 = lane & 15;
    const int b = blockIdx.x;
    const float* Gb = Gws + b * 16512;
    const float* Rb = Gb + 16384;

    // Phase A: stats -> s,t,v,u
    if (t < 128) { tmpA[t] = Gb[t * 128 + t]; tmpB[t] = Rb[t]; }
    __syncthreads();
    if (t < 8) {
        float s2 = 0.f, s1 = 0.f;
#pragma unroll
        for (int k = 0; k < 16; ++k) { s2 += tmpA[t * 16 + k]; s1 += tmpB[t * 16 + k]; }
        const float invN = 1.0f / 262144.0f;
        float mean = s1 * invN;
        float var = s2 * invN - mean * mean;
        red[t] = mean;
        red[8 + t] = rsqrtf(var + 1e-5f);
    }
    __syncthreads();
    if (t < 128) {
        int g = t >> 4;
        float s = gn_w[t] * red[8 + g];
        s_l[t] = s;
        t_l[t] = gn_b[t] - red[g] * s;
    }
    __syncthreads();
    if (t < 128) {
        float v = b_in[t], u = 0.f;
        const float* wr = w_in + t * 128;
#pragma unroll 8
        for (int k = 0; k < 128; ++k) {
            float w = wr[k];
            v += w * t_l[k];
            u += w * s_l[k] * tmpB[k];
        }
        v_l[t] = v; u_l[t] = u;
        vA[b * 128 + t] = v;
    }
    __syncthreads();

    // Phase B: stage As (bf16, swz + global) and G (bf16, swz)
    {
        const float4* w4 = (const float4*)w_in;
        const float4* g4 = (const float4*)Gb;
        unsigned short* abg = Asb + b * 16384;
#pragma unroll
        for (int rep = 0; rep < 16; ++rep) {
            int idx4 = t + rep * 256;
            int c = idx4 >> 5, k0 = (idx4 & 31) * 4;
            int addr = c * 128 + ((((k0 >> 3) ^ (c & 7)) << 3)) + (k0 & 7);
            float4 w = w4[idx4];
            ushort4 o;
            o.x = f2bf(w.x * s_l[k0 + 0]); o.y = f2bf(w.y * s_l[k0 + 1]);
            o.z = f2bf(w.z * s_l[k0 + 2]); o.w = f2bf(w.w * s_l[k0 + 3]);
            *(ushort4*)&As_l[addr] = o;
            *(ushort4*)&abg[c * 128 + k0] = o;
            float4 g = g4[idx4];
            ushort4 og;
            og.x = f2bf(g.x); og.y = f2bf(g.y); og.z = f2bf(g.z); og.w = f2bf(g.w);
            *(ushort4*)&Gb_l[addr] = og;
        }
    }
    __syncthreads();

    // Phase C: P = As @ G  (D[m=c][n=l])
    {
        f32x4 pacc[2][8];
#pragma unroll
        for (int i2 = 0; i2 < 2; ++i2)
#pragma unroll
            for (int j = 0; j < 8; ++j) pacc[i2][j] = (f32x4){0.f, 0.f, 0.f, 0.f};
#pragma unroll
        for (int kk = 0; kk < 4; ++kk) {
            int ch = ((kk * 4 + q) ^ (i16 & 7)) << 3;
            short8 fa[2], fb[8];
#pragma unroll
            for (int i2 = 0; i2 < 2; ++i2)
                fa[i2] = *(const short8*)&As_l[((wv * 2 + i2) * 16 + i16) * 128 + ch];
#pragma unroll
            for (int j = 0; j < 8; ++j)
                fb[j] = *(const short8*)&Gb_l[(j * 16 + i16) * 128 + ch];
#pragma unroll
            for (int i2 = 0; i2 < 2; ++i2)
#pragma unroll
                for (int j = 0; j < 8; ++j)
                    pacc[i2][j] = __builtin_amdgcn_mfma_f32_16x16x32_bf16(fa[i2], fb[j], pacc[i2][j], 0, 0, 0);
        }
        // P -> bf16 LDS [c][l] swz
#pragma unroll
        for (int i2 = 0; i2 < 2; ++i2) {
#pragma unroll
            for (int j = 0; j < 8; ++j) {
#pragma unroll
                for (int r = 0; r < 4; ++r) {
                    int c = (wv * 2 + i2) * 16 + q * 4 + r;
                    int l = j * 16 + i16;
                    Pb_l[c * 128 + ((((l >> 3) ^ (c & 7)) << 3)) + (l & 7)] = f2bf(pacc[i2][j][r]);
                }
            }
        }
    }
    __syncthreads();

    // Phase D: per head S = P_h As_h^T ; logits ; softmax -> Wl
#pragma unroll
    for (int hh = 0; hh < 2; ++hh) {
        int h = wv * 2 + hh;
        f32x4 sacc = (f32x4){0.f, 0.f, 0.f, 0.f};
#pragma unroll
        for (int kk = 0; kk < 4; ++kk) {
            int ch = ((kk * 4 + q) ^ (i16 & 7)) << 3;
            short8 fa = *(const short8*)&Pb_l[(h * 16 + i16) * 128 + ch];
            short8 fb = *(const short8*)&As_l[(h * 16 + i16) * 128 + ch];
            sacc = __builtin_amdgcn_mfma_f32_16x16x32_bf16(fa, fb, sacc, 0, 0, 0);
        }
        int cn = h * 16 + i16;
#pragma unroll
        for (int r = 0; r < 4; ++r) {
            int cm = h * 16 + q * 4 + r;
            float L = 0.25f * (sacc[r] + v_l[cm] * u_l[cn] + u_l[cm] * v_l[cn]
                               + 16384.f * v_l[cm] * v_l[cn]);
            float m = L;
#pragma unroll
            for (int d = 1; d < 16; d <<= 1) m = fmaxf(m, __shfl_xor(m, d, 16));
            float e = __expf(L - m);
            float sum = e;
#pragma unroll
            for (int d = 1; d < 16; d <<= 1) sum += __shfl_xor(sum, d, 16);
            Wl[(h * 16 + q * 4 + r) * 16 + i16] = e / sum;
        }
    }
    __syncthreads();

    // Phase E: w_eff = w_out @ blockdiag(W) -> bf16
    {
        unsigned short* wo = weffb + b * 16384;
#pragma unroll 2
        for (int rep = 0; rep < 64; ++rep) {
            int idx = t + rep * 256;
            int c = idx >> 7, col = idx & 127;
            int h = col >> 4, n = col & 15;
            const float* wr = w_out + c * 128 + h * 16;
            const float* Wr = Wl + h * 256 + n;
            float a = 0.f;
#pragma unroll
            for (int m = 0; m < 16; ++m) a += wr[m] * Wr[m * 16];
            wo[idx] = f2bf(a);
        }
    }
}

// ---------------- K3: GEMM1 + GEMM2 + residual (x kept in LDS) ----------------
__global__ __launch_bounds__(256, 4) void k_out(const float* __restrict__ x,
                                                const unsigned short* __restrict__ Asb,
                                                const float* __restrict__ vA,
                                                const unsigned short* __restrict__ weffb,
                                                const float* __restrict__ b_out,
                                                float* __restrict__ out) {
    __shared__ unsigned short Xs[8192];   // x-stage [p][k] swz, persistent
    __shared__ unsigned short Ht[8192];   // h1^T [p][c] swz, then Hb [c][p] swz
    __shared__ float v_s[128];
    __shared__ float bo_s[128];

    const int t = threadIdx.x;
    const int lane = t & 63, wv = t >> 6;
    const int q = lane >> 4, i16 = lane & 15;
    const int b = blockIdx.x >> 8;
    const int p0 = (blockIdx.x & 255) << 6;
    const float* xb = x + (size_t)b * (128 * NPOS) + p0;

    if (t < 128) { v_s[t] = vA[b * 128 + t]; bo_s[t] = b_out[t]; }

    // stage Xs[p][k] = bf16(x[k][p0+p]); chunk (k>>3) ^ (p&15)
    {
        const int p = t & 63;
        const int sw = p & 15;
        const int kq0 = t >> 6;
#pragma unroll
        for (int i = 0; i < 4; ++i) {
            int kq = kq0 + i * 4;
            const float* col = xb + (size_t)(kq * 8) * NPOS + p;
            short8 o;
#pragma unroll
            for (int e = 0; e < 8; ++e)
                ((unsigned short*)&o)[e] = f2bf(col[(size_t)e * NPOS]);
            *(short8*)&Xs[p * 128 + ((kq ^ sw) << 3)] = o;
        }
    }
    __syncthreads();

    // GEMM1: A = Asb (global), B = Xs
    const unsigned short* ab = Asb + b * 16384;
    f32x4 acc1[2][4];
#pragma unroll
    for (int a = 0; a < 2; ++a)
#pragma unroll
        for (int pt = 0; pt < 4; ++pt) acc1[a][pt] = (f32x4){0.f, 0.f, 0.f, 0.f};

#pragma unroll
    for (int ks = 0; ks < 4; ++ks) {
        short8 a0 = *(const short8*)&ab[(wv * 32 + i16) * 128 + ks * 32 + q * 8];
        short8 a1 = *(const short8*)&ab[(wv * 32 + 16 + i16) * 128 + ks * 32 + q * 8];
        const int cb = ((ks * 4 + q) ^ i16) << 3;
#pragma unroll
        for (int pt = 0; pt < 4; ++pt) {
            short8 bb = *(const short8*)&Xs[(pt * 16 + i16) * 128 + cb];
            acc1[0][pt] = __builtin_amdgcn_mfma_f32_16x16x32_bf16(a0, bb, acc1[0][pt], 0, 0, 0);
            acc1[1][pt] = __builtin_amdgcn_mfma_f32_16x16x32_bf16(a1, bb, acc1[1][pt], 0, 0, 0);
        }
    }

    // h1^T -> Ht[p][c] (+v), chunk swizzle (c>>3) ^ (p&15)
#pragma unroll
    for (int a = 0; a < 2; ++a) {
        int cb0 = wv * 32 + a * 16 + q * 4;
#pragma unroll
        for (int pt = 0; pt < 4; ++pt) {
            int p = pt * 16 + i16;
#pragma unroll
            for (int r = 0; r < 4; ++r) {
                int c = cb0 + r;
                Ht[p * 128 + ((((c >> 3) ^ i16) << 3)) + (c & 7)] =
                    f2bf(acc1[a][pt][r] + v_s[c]);
            }
        }
    }
    __syncthreads();

    // GEMM2: A = weff (global), B = h1^T (LDS)
    const unsigned short* ab2 = weffb + b * 16384;
    f32x4 acc2[2][4];
#pragma unroll
    for (int a = 0; a < 2; ++a)
#pragma unroll
        for (int pt = 0; pt < 4; ++pt) acc2[a][pt] = (f32x4){0.f, 0.f, 0.f, 0.f};

#pragma unroll
    for (int ks = 0; ks < 4; ++ks) {
        short8 a0 = *(const short8*)&ab2[(wv * 32 + i16) * 128 + ks * 32 + q * 8];
        short8 a1 = *(const short8*)&ab2[(wv * 32 + 16 + i16) * 128 + ks * 32 + q * 8];
        const int cb = ((ks * 4 + q) ^ i16) << 3;
#pragma unroll
        for (int pt = 0; pt < 4; ++pt) {
            short8 bb = *(const short8*)&Ht[(pt * 16 + i16) * 128 + cb];
            acc2[0][pt] = __builtin_amdgcn_mfma_f32_16x16x32_bf16(a0, bb, acc2[0][pt], 0, 0, 0);
            acc2[1][pt] = __builtin_amdgcn_mfma_f32_16x16x32_bf16(a1, bb, acc2[1][pt], 0, 0, 0);
        }
    }
    __syncthreads();

    // Hb[c][p] = acc2 + b_out, p-chunk swizzle (p>>3) ^ (c&7)
#pragma unroll
    for (int a = 0; a < 2; ++a) {
        int cb0 = wv * 32 + a * 16 + q * 4;
#pragma unroll
        for (int pt = 0; pt < 4; ++pt) {
            int p = pt * 16 + i16;
#pragma unroll
            for (int r = 0; r < 4; ++r) {
                int c = cb0 + r;
                Ht[c * 64 + ((((p >> 3) ^ (c & 7)) << 3)) + (p & 7)] =
                    f2bf(acc2[a][pt][r] + bo_s[c]);
            }
        }
    }
    __syncthreads();

    // epilogue: out = x(LDS bf16) + h ; float4 stores
    float* ob = out + (size_t)b * (128 * NPOS) + p0;
#pragma unroll
    for (int i = 0; i < 8; ++i) {
        int idx = t + i * 256;
        int c = idx >> 4, p4 = idx & 15;
        int p = p4 * 4;
        ushort4 hv = *(const ushort4*)&Ht[c * 64 + ((((p >> 3) ^ (c & 7)) << 3)) + (p & 7)];
        float4 o;
        o.x = bf2f(Xs[(p + 0) * 128 + ((((c >> 3) ^ ((p + 0) & 15)) << 3)) + (c & 7)]) + bf2f(hv.x);
        o.y = bf2f(Xs[(p + 1) * 128 + ((((c >> 3) ^ ((p + 1) & 15)) << 3)) + (c & 7)]) + bf2f(hv.y);
        o.z = bf2f(Xs[(p + 2) * 128 + ((((c >> 3) ^ ((p + 2) & 15)) << 3)) + (c & 7)]) + bf2f(hv.z);
        o.w = bf2f(Xs[(p + 3) * 128 + ((((c >> 3) ^ ((p + 3) & 15)) << 3)) + (c & 7)]) + bf2f(hv.w);
        *(float4*)&ob[(size_t)c * NPOS + p] = o;
    }
}

extern "C" void kernel_launch(void* const* d_in, const int* in_sizes, int n_in,
                              void* d_out, int out_size, void* d_ws, size_t ws_size,
                              hipStream_t stream) {
    const float* x    = (const float*)d_in[0];
    const float* gn_w = (const float*)d_in[1];
    const float* gn_b = (const float*)d_in[2];
    const float* w_in = (const float*)d_in[3];
    const float* b_in = (const float*)d_in[4];
    const float* w_out= (const float*)d_in[5];
    const float* b_out= (const float*)d_in[6];
    float* out = (float*)d_out;

    float* ws = (float*)d_ws;
    float* Gws = ws;                                          // 8 x (16384 G + 128 R)
    float* vA  = ws + 132096;                                 // 1024 f
    unsigned short* Asb   = (unsigned short*)(ws + 133120);   // 131072 us
    unsigned short* weffb = (unsigned short*)(ws + 198656);   // 131072 us

    hipMemsetAsync(d_ws, 0, 132096 * sizeof(float), stream);
    k_gram<<<dim3(512), dim3(1024), 0, stream>>>(x, Gws);
    k_prep2<<<dim3(8), dim3(256), 0, stream>>>(Gws, gn_w, gn_b, w_in, b_in, w_out,
                                               vA, Asb, weffb);
    k_out<<<dim3(2048), dim3(256), 0, stream>>>(x, Asb, vA, weffb, b_out, out);
}